// Round 12
// baseline (284.291 us; speedup 1.0000x reference)
//
#include <hip/hip_runtime.h>
#include <hip/hip_fp16.h>

#define N_NODES 100000
#define N_EDGES 1600000
#define N_GRAPHS 128
#define SB 391               // 256-node buckets
#define CAP 4608             // padded bucket capacity (mean 4096 + 8 sigma)
#define NBLK 512             // blocks for the fused scatter pass
#define NE4 (N_EDGES / 4)    // 400000 int4
#define CH4 782              // int4 per block (512*782 >= 400000)
#define LDX 136              // LDS stride (halves) for MFMA staging

typedef unsigned long long u64;
typedef unsigned int u32;
typedef unsigned char u8;
typedef _Float16 f16;
typedef f16 half8 __attribute__((ext_vector_type(8)));
typedef f16 half4v __attribute__((ext_vector_type(4)));
typedef float floatx4 __attribute__((ext_vector_type(4)));

// ---------------- P0: init global bucket cursors ----------------
__global__ void k_init(int* __restrict__ cur_d, int* __restrict__ cur_s) {
  int t = blockIdx.x * blockDim.x + threadIdx.x;
  if (t < SB) { cur_d[t] = t * CAP; cur_s[t] = t * CAP; }
}

// ---------------- P1: fused count + reserve + scatter into padded buckets ----------
__global__ __launch_bounds__(256) void k_fuse(const int4* __restrict__ src4,
                                              const int4* __restrict__ dst4,
                                              int* __restrict__ cur_d,
                                              int* __restrict__ cur_s,
                                              u32* __restrict__ ed,
                                              u8* __restrict__ ssk8) {
  __shared__ int hd[SB], hs[SB], ld[SB], ls[SB];
  const int t = threadIdx.x, b = blockIdx.x;
  for (int j = t; j < SB; j += 256) { hd[j] = 0; hs[j] = 0; }
  __syncthreads();
  const int start = b * CH4, end = min(start + CH4, NE4);
  // pass A: count
  for (int i = start + t; i < end; i += 256) {
    int4 d = dst4[i]; int4 s = src4[i];
    atomicAdd(&hd[d.x >> 8], 1); atomicAdd(&hd[d.y >> 8], 1);
    atomicAdd(&hd[d.z >> 8], 1); atomicAdd(&hd[d.w >> 8], 1);
    atomicAdd(&hs[s.x >> 8], 1); atomicAdd(&hs[s.y >> 8], 1);
    atomicAdd(&hs[s.z >> 8], 1); atomicAdd(&hs[s.w >> 8], 1);
  }
  __syncthreads();
  // reserve ranges (one global atomic per bucket per block)
  for (int j = t; j < SB; j += 256) {
    ld[j] = atomicAdd(&cur_d[j], hd[j]);
    ls[j] = atomicAdd(&cur_s[j], hs[j]);
  }
  __syncthreads();
  // pass B: scatter (chunk is L2-warm)
  for (int i = start + t; i < end; i += 256) {
    int4 d4 = dst4[i]; int4 s4 = src4[i];
    {
      int d = d4.x, s = s4.x;
      int pd = atomicAdd(&ld[d >> 8], 1);
      ed[pd] = ((u32)(d & 255) << 24) | (u32)s;
      int ps = atomicAdd(&ls[s >> 8], 1);
      ssk8[ps] = (u8)(s & 255);
    }
    {
      int d = d4.y, s = s4.y;
      int pd = atomicAdd(&ld[d >> 8], 1);
      ed[pd] = ((u32)(d & 255) << 24) | (u32)s;
      int ps = atomicAdd(&ls[s >> 8], 1);
      ssk8[ps] = (u8)(s & 255);
    }
    {
      int d = d4.z, s = s4.z;
      int pd = atomicAdd(&ld[d >> 8], 1);
      ed[pd] = ((u32)(d & 255) << 24) | (u32)s;
      int ps = atomicAdd(&ls[s >> 8], 1);
      ssk8[ps] = (u8)(s & 255);
    }
    {
      int d = d4.w, s = s4.w;
      int pd = atomicAdd(&ld[d >> 8], 1);
      ed[pd] = ((u32)(d & 255) << 24) | (u32)s;
      int ps = atomicAdd(&ls[s >> 8], 1);
      ssk8[ps] = (u8)(s & 255);
    }
  }
}

// ------ P2: per-bucket CSR finalize + degrees/norms (padded bucket space) ----------
__global__ __launch_bounds__(256) void k_bucket_csr(const u32* __restrict__ ed,
                                                    const u8* __restrict__ ssk8,
                                                    const int* __restrict__ cur_d,
                                                    const int* __restrict__ cur_s,
                                                    int* __restrict__ row_ptr,
                                                    int* __restrict__ deg,
                                                    float* __restrict__ norm_in,
                                                    float* __restrict__ norm_out,
                                                    int* __restrict__ edge_src) {
  __shared__ int hist[256], scanbuf[256], cursor[256], hist2[256];
  const int b = blockIdx.x, t = threadIdx.x;
  const int base = b << 8;
  const int lo = b * CAP;
  const int hiD = cur_d[b];        // lo + count_d
  const int hiS = cur_s[b];        // lo + count_s
  hist[t] = 0; hist2[t] = 0;
  __syncthreads();
  for (int i = lo + t; i < hiS; i += 256) atomicAdd(&hist2[ssk8[i]], 1);
  for (int i = lo + t; i < hiD; i += 256) atomicAdd(&hist[ed[i] >> 24], 1);
  __syncthreads();
  int node = base + t;
  if (node < N_NODES)
    norm_out[node] = rsqrtf(fmaxf((float)hist2[t], 1.0f));
  int v = hist[t];
  scanbuf[t] = v;
  __syncthreads();
  for (int off = 1; off < 256; off <<= 1) {
    int a = (t >= off) ? scanbuf[t - off] : 0;
    __syncthreads(); scanbuf[t] += a; __syncthreads();
  }
  int excl = scanbuf[t] - v;
  if (node < N_NODES) {
    row_ptr[node] = lo + excl;
    deg[node] = v;
    norm_in[node] = rsqrtf(fmaxf((float)v, 1.0f));
  }
  cursor[t] = excl;
  __syncthreads();
  for (int i = lo + t; i < hiD; i += 256) {
    u32 e = ed[i];
    int p = atomicAdd(&cursor[e >> 24], 1);
    edge_src[lo + p] = (int)(e & 0x00FFFFFFu);
  }
}

// ---------------- P3: gemm1 (MFMA fp16): h1 = (x * norm_out) @ W1 -> fp16 ----------
__global__ __launch_bounds__(256) void k_gemm1(const float* __restrict__ x,
                                               const float* __restrict__ W1,
                                               const float* __restrict__ norm_out,
                                               __half* __restrict__ h1h) {
  __shared__ __align__(16) f16 Xs[64 * LDX];
  __shared__ __align__(16) f16 Ws[64 * LDX];
  const int t = threadIdx.x;
  const int row0 = blockIdx.x * 64;

  const float4* W4 = (const float4*)W1;     // 2048 float4 = [k][n4]
  for (int i = t; i < 2048; i += 256) {
    int k = i >> 4, n4 = (i & 15) * 4;
    float4 v = W4[i];
    Ws[(n4 + 0) * LDX + k] = (f16)v.x;
    Ws[(n4 + 1) * LDX + k] = (f16)v.y;
    Ws[(n4 + 2) * LDX + k] = (f16)v.z;
    Ws[(n4 + 3) * LDX + k] = (f16)v.w;
  }
  const float4* x4 = (const float4*)x;
  #pragma unroll
  for (int i = 0; i < 8; ++i) {
    int idx = t + 256 * i;                  // 0..2047
    int r = idx >> 5, c4 = idx & 31;
    int row = row0 + r;
    float4 v = make_float4(0.f, 0.f, 0.f, 0.f);
    if (row < N_NODES) {
      float s = norm_out[row];
      v = x4[(size_t)row * 32 + c4];
      v.x *= s; v.y *= s; v.z *= s; v.w *= s;
    }
    half4v h = { (f16)v.x, (f16)v.y, (f16)v.z, (f16)v.w };
    *(half4v*)&Xs[r * LDX + c4 * 4] = h;
  }
  __syncthreads();

  const int w = t >> 6, l = t & 63;
  const int m = l & 15, quad = l >> 4;
  floatx4 c0 = {0.f,0.f,0.f,0.f}, c1 = {0.f,0.f,0.f,0.f};
  floatx4 c2 = {0.f,0.f,0.f,0.f}, c3 = {0.f,0.f,0.f,0.f};
  const f16* xrow = &Xs[(w * 16 + m) * LDX + quad * 8];
  const f16* wrow = &Ws[m * LDX + quad * 8];
  #pragma unroll
  for (int kb = 0; kb < 4; ++kb) {
    half8 a  = *(const half8*)(xrow + kb * 32);
    half8 b0 = *(const half8*)(wrow + kb * 32);
    half8 b1 = *(const half8*)(wrow + 16 * LDX + kb * 32);
    half8 b2 = *(const half8*)(wrow + 32 * LDX + kb * 32);
    half8 b3 = *(const half8*)(wrow + 48 * LDX + kb * 32);
    c0 = __builtin_amdgcn_mfma_f32_16x16x32_f16(a, b0, c0, 0, 0, 0);
    c1 = __builtin_amdgcn_mfma_f32_16x16x32_f16(a, b1, c1, 0, 0, 0);
    c2 = __builtin_amdgcn_mfma_f32_16x16x32_f16(a, b2, c2, 0, 0, 0);
    c3 = __builtin_amdgcn_mfma_f32_16x16x32_f16(a, b3, c3, 0, 0, 0);
  }
  #pragma unroll
  for (int r = 0; r < 4; ++r) {
    int row = row0 + w * 16 + quad * 4 + r;
    if (row < N_NODES + 1) {                // includes zeros dummy row N_NODES
      __half* dst = h1h + (size_t)row * 64 + m;
      dst[0]  = __float2half(c0[r]);
      dst[16] = __float2half(c1[r]);
      dst[32] = __float2half(c2[r]);
      dst[48] = __float2half(c3[r]);
    }
  }
}

// ---------------- P4: fused gather(h1) -> relu(.*norm_in + b1) -> @W2 * norm_out -> h2
// one wave per node; 32 lanes/edge (u32 = 2 fp16 feats); packed-fp16 accumulation
__global__ __launch_bounds__(256) void k_gather_l1(const int* __restrict__ row_ptr,
                                                   const int* __restrict__ deg,
                                                   const int* __restrict__ edge_src,
                                                   const __half* __restrict__ h1h,
                                                   const float* __restrict__ norm_in,
                                                   const float* __restrict__ norm_out,
                                                   const float* __restrict__ b1,
                                                   const float* __restrict__ W2,
                                                   __half* __restrict__ h2h) {
  __shared__ float W2s[64 * 17];   // padded stride 17
  const int t = threadIdx.x;
  for (int i = t; i < 64 * 16; i += 256) W2s[(i >> 4) * 17 + (i & 15)] = W2[i];
  if (blockIdx.x == 0 && t < 16) h2h[(size_t)N_NODES * 16 + t] = __float2half(0.f);
  __syncthreads();

  const int w = t >> 6;
  const int l = t & 63;
  const int n = blockIdx.x * 4 + w;
  const int hf = l >> 5;           // which edge of each pair
  const u32 c = (u32)(l & 31);     // feature-pair index within row

  const u32* __restrict__ h1u = (const u32*)h1h;
  const int lo = row_ptr[n], hi = lo + deg[n];

  __half2 a0 = {0,0}, a1 = {0,0}, a2 = {0,0}, a3 = {0,0};
  __half2 a4 = {0,0}, a5 = {0,0}, a6 = {0,0}, a7 = {0,0};
  for (int i = lo; i < hi; i += 16) {
    int idx = i + (l & 15);
    int sv = (idx < hi) ? edge_src[idx] : (int)N_NODES;   // clamp to zeros row
    int s0 = __shfl(sv,  0 + hf, 64);
    int s1 = __shfl(sv,  2 + hf, 64);
    int s2 = __shfl(sv,  4 + hf, 64);
    int s3 = __shfl(sv,  6 + hf, 64);
    int s4 = __shfl(sv,  8 + hf, 64);
    int s5 = __shfl(sv, 10 + hf, 64);
    int s6 = __shfl(sv, 12 + hf, 64);
    int s7 = __shfl(sv, 14 + hf, 64);
    u32 v0 = h1u[(u32)s0 * 32u + c];
    u32 v1 = h1u[(u32)s1 * 32u + c];
    u32 v2 = h1u[(u32)s2 * 32u + c];
    u32 v3 = h1u[(u32)s3 * 32u + c];
    u32 v4 = h1u[(u32)s4 * 32u + c];
    u32 v5 = h1u[(u32)s5 * 32u + c];
    u32 v6 = h1u[(u32)s6 * 32u + c];
    u32 v7 = h1u[(u32)s7 * 32u + c];
    a0 = __hadd2(a0, *(__half2*)&v0);
    a1 = __hadd2(a1, *(__half2*)&v1);
    a2 = __hadd2(a2, *(__half2*)&v2);
    a3 = __hadd2(a3, *(__half2*)&v3);
    a4 = __hadd2(a4, *(__half2*)&v4);
    a5 = __hadd2(a5, *(__half2*)&v5);
    a6 = __hadd2(a6, *(__half2*)&v6);
    a7 = __hadd2(a7, *(__half2*)&v7);
  }
  float2 f0 = __half22float2(a0), f1 = __half22float2(a1);
  float2 f2 = __half22float2(a2), f3 = __half22float2(a3);
  float2 f4 = __half22float2(a4), f5 = __half22float2(a5);
  float2 f6 = __half22float2(a6), f7 = __half22float2(a7);
  float accx = ((f0.x + f1.x) + (f2.x + f3.x)) + ((f4.x + f5.x) + (f6.x + f7.x));
  float accy = ((f0.y + f1.y) + (f2.y + f3.y)) + ((f4.y + f5.y) + (f6.y + f7.y));
  accx += __shfl_xor(accx, 32, 64);
  accy += __shfl_xor(accy, 32, 64);

  const float ni = norm_in[n];
  const float2 bb = ((const float2*)b1)[c];
  float h1x = fmaxf(accx * ni + bb.x, 0.0f);
  float h1y = fmaxf(accy * ni + bb.y, 0.0f);

  const int j = l & 15, p = l >> 4;
  float partial = 0.f;
  #pragma unroll
  for (int kk = 0; kk < 16; kk += 2) {
    int sl = p * 8 + (kk >> 1);
    float vx = __shfl(h1x, sl, 64);
    float vy = __shfl(h1y, sl, 64);
    partial += vx * W2s[(p * 16 + kk) * 17 + j];
    partial += vy * W2s[(p * 16 + kk + 1) * 17 + j];
  }
  partial += __shfl_xor(partial, 16, 64);
  partial += __shfl_xor(partial, 32, 64);
  if (l < 16) h2h[(size_t)n * 16 + l] = __float2half(norm_out[n] * partial);
}

// ---------------- P5: gather layer2: agg2 = norm_in * sum_edges h2[src] (16 feats) ------
__global__ __launch_bounds__(256) void k_gather_l2(const int* __restrict__ row_ptr,
                                                   const int* __restrict__ deg,
                                                   const int* __restrict__ edge_src,
                                                   const __half* __restrict__ h2h,
                                                   const float* __restrict__ norm_in,
                                                   float* __restrict__ agg2) {
  const int t = threadIdx.x;
  const int w = t >> 6;
  const int l = t & 63;
  const int n = blockIdx.x * 4 + w;
  const int f2 = l & 7;
  const int p = l >> 3;            // 8 edge slices

  const u32* __restrict__ h2u = (const u32*)h2h;
  const int lo = row_ptr[n], hi = lo + deg[n];

  __half2 aa = {0,0}, ab = {0,0};
  for (int base = lo; base < hi; base += 16) {
    int i1 = base + p, i2 = base + p + 8;
    int s0 = (i1 < hi) ? edge_src[i1] : (int)N_NODES;
    int s1 = (i2 < hi) ? edge_src[i2] : (int)N_NODES;
    u32 v0 = h2u[(u32)s0 * 8u + (u32)f2];
    u32 v1 = h2u[(u32)s1 * 8u + (u32)f2];
    aa = __hadd2(aa, *(__half2*)&v0);
    ab = __hadd2(ab, *(__half2*)&v1);
  }
  float2 g0 = __half22float2(aa), g1 = __half22float2(ab);
  float sx = g0.x + g1.x, sy = g0.y + g1.y;
  sx += __shfl_xor(sx, 8, 64);  sy += __shfl_xor(sy, 8, 64);
  sx += __shfl_xor(sx, 16, 64); sy += __shfl_xor(sy, 16, 64);
  sx += __shfl_xor(sx, 32, 64); sy += __shfl_xor(sy, 32, 64);
  if (l < 8) {
    float ni = norm_in[n];
    ((float2*)agg2)[(size_t)n * 8 + f2] = make_float2(sx * ni, sy * ni);
  }
}

// ---------------- P6: per-graph mean pool (gid sorted, no atomics) ----------------
__global__ __launch_bounds__(256) void k_pool(const float* __restrict__ agg2,
                                              const float* __restrict__ b2,
                                              const int* __restrict__ gid,
                                              float* __restrict__ out) {
  const int g = blockIdx.x;
  __shared__ int s_lo, s_hi;
  if (threadIdx.x == 0) {
    int a = 0, b = N_NODES;
    while (a < b) { int m = (a + b) >> 1; if (gid[m] < g) a = m + 1; else b = m; }
    s_lo = a;
    b = N_NODES;
    while (a < b) { int m = (a + b) >> 1; if (gid[m] < g + 1) a = m + 1; else b = m; }
    s_hi = a;
  }
  __syncthreads();
  const int lo = s_lo, hi = s_hi, cnt = hi - lo;
  const int j = threadIdx.x & 15;
  const int r = threadIdx.x >> 4;
  float acc = 0.f;
  for (int n = lo + r; n < hi; n += 16)
    acc += agg2[(size_t)n * 16 + j];

  __shared__ float red[256];
  red[threadIdx.x] = acc;
  __syncthreads();
  #pragma unroll
  for (int s = 8; s > 0; s >>= 1) {
    if (r < s) red[threadIdx.x] += red[threadIdx.x + s * 16];
    __syncthreads();
  }
  if (r == 0)
    out[g * 16 + j] = (cnt > 0) ? (red[j] / (float)cnt + b2[j]) : 0.0f;
}

extern "C" void kernel_launch(void* const* d_in, const int* in_sizes, int n_in,
                              void* d_out, int out_size, void* d_ws, size_t ws_size,
                              hipStream_t stream) {
  const float* x   = (const float*)d_in[0];
  const float* W1  = (const float*)d_in[1];
  const float* b1  = (const float*)d_in[2];
  const float* W2  = (const float*)d_in[3];
  const float* b2  = (const float*)d_in[4];
  const int*   src = (const int*)d_in[5];
  const int*   dst = (const int*)d_in[6];
  const int*   gid = (const int*)d_in[7];
  float* out = (float*)d_out;

  int* wsi = (int*)d_ws;
  float* wsf = (float*)d_ws;

  // word-offset layout (~24.8 MB):
  float* norm_out = wsf + 0;                 // [N]
  float* norm_in  = wsf + 100000;            // [N]
  int*   row_ptr  = wsi + 200000;            // [N]
  int*   deg      = wsi + 300000;            // [N]
  int*   cur_d    = wsi + 400000;            // [SB+pad]
  int*   cur_s    = wsi + 400400;            // [SB+pad]
  int*   edge_src = wsi + 400800;            // [SB*CAP = 1801728] padded bucket space
  const size_t S  = 2202528;                 // scratch base (words)
  // sort scratch (dead after k_bucket_csr):
  u8*    ssk8     = (u8*)(wsi + S);          // [SB*CAP bytes = 450432 words]
  u32*   ed       = (u32*)(wsi + S + 450432);// [SB*CAP = 1801728]
  // reuse after CSR build: h1h over {ssk8,ed}; agg2 over dead h1h; h2h after h1h
  __half* h1h     = (__half*)(wsi + S);            // [(N+1)*64 halves = 3200032 words]
  __half* h2h     = (__half*)(wsi + S + 3200032);  // [(N+1)*16 halves = 800008 words]
  float*  agg2    = (float*)(wsi + S);             // [16N words] (h1h dead by then)

  const int4* src4 = (const int4*)src;
  const int4* dst4 = (const int4*)dst;

  k_init      <<<2, 256, 0, stream>>>(cur_d, cur_s);
  k_fuse      <<<NBLK, 256, 0, stream>>>(src4, dst4, cur_d, cur_s, ed, ssk8);
  k_bucket_csr<<<SB, 256, 0, stream>>>(ed, ssk8, cur_d, cur_s, row_ptr, deg,
                                       norm_in, norm_out, edge_src);
  k_gemm1     <<<(N_NODES + 64) / 64, 256, 0, stream>>>(x, W1, norm_out, h1h);
  k_gather_l1 <<<N_NODES / 4, 256, 0, stream>>>(row_ptr, deg, edge_src, h1h,
                                                norm_in, norm_out, b1, W2, h2h);
  k_gather_l2 <<<N_NODES / 4, 256, 0, stream>>>(row_ptr, deg, edge_src, h2h,
                                                norm_in, agg2);
  k_pool      <<<N_GRAPHS, 256, 0, stream>>>(agg2, b2, gid, out);
}